// Round 8
// baseline (161.959 us; speedup 1.0000x reference)
//
#include <hip/hip_runtime.h>

#define BB 512
#define TT 512
#define KK 128

typedef __attribute__((ext_vector_type(8))) short short8;   // 8 x bf16 bits
typedef __attribute__((ext_vector_type(4))) float f32x4;

// f32 -> bf16 bits, round-to-nearest-even (finite values)
__device__ __forceinline__ unsigned short f2bf(float f) {
  unsigned u = __float_as_uint(f);
  unsigned r = ((u >> 16) & 1u) + 0x7fffu;
  return (unsigned short)((u + r) >> 16);
}
__device__ __forceinline__ float bf2f(unsigned short h) {
  return __uint_as_float(((unsigned)h) << 16);
}

// One block per batch element, 128 threads = 2 INDEPENDENT waves.
// Wave 0 (dir=0): forward   w_t = u_t . (E^T w_{t-1}),   t = 1..256   (256 steps)
// Wave 1 (dir=1): backward  z_{t-1} = u_{t-1} . (E z_t), t = 510..257 (254 steps)
//                 + final plain step y = E z_257;  Z = w_256 . y.
// Each wave does the FULL K=128 matvec per step: 8 col-tiles x 4 k-chunks =
// 32 row-replicated 16x16x32 bf16 MFMAs (A chunk broadcast to all rows).
// NO barriers in the loop: intra-wave LDS ops are program-ordered; scale
// exponent d lives in an SGPR via readfirstlane. Scaled bf16 state in LDS:
//   stored_new = matvec * 2^(pot*C - d),  d = exponent of previous stored[0],
//   M += d;  true value = stored * 2^M.
__global__ __launch_bounds__(128, 1) void crf_fwd_kernel(
    const float* __restrict__ pot, const int* __restrict__ tags,
    const float* __restrict__ trans, float* __restrict__ out) {
  const float C = 1.4426950408889634f;    // 1/ln2
  const float LN2 = 0.6931471805599453f;
  const int b = blockIdx.x;
  const int tid = threadIdx.x;            // 0..127
  const int lane = tid & 63;
  const int dir = tid >> 6;               // 0 = fwd wave, 1 = bwd wave
  const int lg = lane >> 4;               // k-chunk group 0..3
  const int lc = lane & 15;               // column within 16-tile

  __shared__ alignas(16) unsigned short sbuf[2][2][KK];  // [dir][parity][j]
  __shared__ float red[4];                // score_f, score_b, Mf, Mb

  const float* pb = pot + (size_t)b * TT * KK;

  // ---- sequence score: thread tid covers t in [4tid, 4tid+4) ----
  float sc;
  {
    int base = 4 * tid;
    int4 tg = *(const int4*)&tags[b * TT + base];
    sc = pb[(size_t)(base + 0) * KK + tg.x] + pb[(size_t)(base + 1) * KK + tg.y]
       + pb[(size_t)(base + 2) * KK + tg.z] + pb[(size_t)(base + 3) * KK + tg.w];
    sc += trans[tg.x * KK + tg.y] + trans[tg.y * KK + tg.z] +
          trans[tg.z * KK + tg.w];
    if (base + 4 < TT) sc += trans[tg.w * KK + tags[b * TT + base + 4]];
  }
  #pragma unroll
  for (int off = 32; off; off >>= 1) sc += __shfl_xor(sc, off, 64);
  if (lane == 0) red[dir] = sc;

  // ---- B fragments: 8 tiles x 4 k-chunks (fwd: E[k][j]; bwd: transposed) ----
  short8 Bf[8][4];
  #pragma unroll
  for (int q = 0; q < 8; ++q) {
    #pragma unroll
    for (int kc = 0; kc < 4; ++kc) {
      #pragma unroll
      for (int e = 0; e < 8; ++e) {
        int k = 32 * kc + 8 * lg + e;
        int j = 16 * q + lc;
        float tv = (dir == 0) ? trans[k * KK + j] : trans[j * KK + k];
        Bf[q][kc][e] = (short)f2bf(__builtin_amdgcn_exp2f(tv * C));
      }
    }
  }

  const int cA = 32 * lg + lc;            // this lane's epilogue columns
  const int cB = cA + 16;
  const int nst = dir ? 255 : 256;
  const int r0 = dir ? (TT - 2) : 1;
  const int st = dir ? -1 : 1;

  // ---- init: fwd u_0, bwd u_511 ----
  int d;
  {
    int ri = dir ? (TT - 1) : 0;
    float va = __builtin_amdgcn_exp2f(pb[(size_t)ri * KK + cA] * C);
    float vb = __builtin_amdgcn_exp2f(pb[(size_t)ri * KK + cB] * C);
    sbuf[dir][0][cA] = f2bf(va);
    sbuf[dir][0][cB] = f2bf(vb);
    unsigned u0 = __builtin_amdgcn_readfirstlane(__float_as_uint(va));
    d = (int)((u0 >> 23) & 0xFF) - 127;
  }

  float M = 0.f;
  // 3-deep pot prefetch pipeline (2 columns per lane)
  float pA0 = pb[(size_t)r0 * KK + cA];
  float pA1 = pb[(size_t)r0 * KK + cB];
  float pB0 = pb[(size_t)(r0 + st) * KK + cA];
  float pB1 = pb[(size_t)(r0 + st) * KK + cB];
  float pC0 = pb[(size_t)(r0 + 2 * st) * KK + cA];
  float pC1 = pb[(size_t)(r0 + 2 * st) * KK + cB];

  for (int it = 0; it < nst; ++it) {
    const int p = it & 1, w = p ^ 1;
    const unsigned short* wp = &sbuf[dir][p][0];
    short8 A0 = *(const short8*)(wp + 8 * lg);        // w[   8lg + e]
    short8 A1 = *(const short8*)(wp + 32 + 8 * lg);   // w[32+8lg + e]
    short8 A2 = *(const short8*)(wp + 64 + 8 * lg);
    short8 A3 = *(const short8*)(wp + 96 + 8 * lg);
    int rn = r0 + st * (it + 3);
    rn = (rn < 0) ? 0 : (rn > TT - 1 ? TT - 1 : rn);
    float pN0 = pb[(size_t)rn * KK + cA];             // prefetch pot 3 ahead
    float pN1 = pb[(size_t)rn * KK + cB];
    const f32x4 z4 = {0.f, 0.f, 0.f, 0.f};
    f32x4 a0, a1, a2, a3, a4, a5, a6, a7;
    __builtin_amdgcn_s_setprio(1);
    #define TILE(acc, q)                                                  \
      acc = __builtin_amdgcn_mfma_f32_16x16x32_bf16(A3, Bf[q][3], z4, 0, 0, 0); \
      acc = __builtin_amdgcn_mfma_f32_16x16x32_bf16(A2, Bf[q][2], acc, 0, 0, 0); \
      acc = __builtin_amdgcn_mfma_f32_16x16x32_bf16(A1, Bf[q][1], acc, 0, 0, 0); \
      acc = __builtin_amdgcn_mfma_f32_16x16x32_bf16(A0, Bf[q][0], acc, 0, 0, 0);
    TILE(a0, 0) TILE(a1, 1) TILE(a2, 2) TILE(a3, 3)
    TILE(a4, 4) TILE(a5, 5) TILE(a6, 6) TILE(a7, 7)
    #undef TILE
    __builtin_amdgcn_s_setprio(0);
    // lane's own tiles: qa = 2lg (col cA), qb = 2lg+1 (col cB)
    float Sa = (lg == 0) ? a0[0] : ((lg == 1) ? a2[0] : ((lg == 2) ? a4[0] : a6[0]));
    float Sb = (lg == 0) ? a1[0] : ((lg == 1) ? a3[0] : ((lg == 2) ? a5[0] : a7[0]));
    const bool lastB = (dir == 1) && (it == nst - 1);  // y = E z (no u factor)
    float pea = lastB ? 0.f : pA0;
    float peb = lastB ? 0.f : pA1;
    float fd = (float)(-d);
    float va = Sa * __builtin_amdgcn_exp2f(fmaf(pea, C, fd));
    float vb = Sb * __builtin_amdgcn_exp2f(fmaf(peb, C, fd));
    M += (float)d;
    sbuf[dir][w][cA] = f2bf(va);
    sbuf[dir][w][cB] = f2bf(vb);
    unsigned u0 = __builtin_amdgcn_readfirstlane(__float_as_uint(va));
    d = (int)((u0 >> 23) & 0xFF) - 127;               // lane 0 holds col 0
    pA0 = pB0; pA1 = pB1; pB0 = pC0; pB1 = pC1; pC0 = pN0; pC1 = pN1;
  }

  if (lane == 0) red[2 + dir] = M;
  __syncthreads();   // the ONLY block-wide sync: meet point

  // ---- meet: Z * 2^(Mf+Mb) = sum_j wF[j] * y[j] ----
  // fwd final: it=255 wrote parity 0;  bwd final: it=254 wrote parity 1.
  if (dir == 0) {
    float pr = bf2f(sbuf[0][0][lane]) * bf2f(sbuf[1][1][lane])
             + bf2f(sbuf[0][0][lane + 64]) * bf2f(sbuf[1][1][lane + 64]);
    #pragma unroll
    for (int off = 32; off; off >>= 1) pr += __shfl_xor(pr, off, 64);
    if (lane == 0) {
      float logZ = (red[2] + red[3] + __builtin_amdgcn_logf(pr)) * LN2;
      out[b] = (red[0] + red[1]) - logZ;
    }
  }
}

extern "C" void kernel_launch(void* const* d_in, const int* in_sizes, int n_in,
                              void* d_out, int out_size, void* d_ws, size_t ws_size,
                              hipStream_t stream) {
  const float* pot = (const float*)d_in[0];
  const int* tags = (const int*)d_in[1];
  const float* trans = (const float*)d_in[2];
  float* out = (float*)d_out;
  crf_fwd_kernel<<<BB, 128, 0, stream>>>(pot, tags, trans, out);
}

// Round 9
// 148.618 us; speedup vs baseline: 1.0898x; 1.0898x over previous
//
#include <hip/hip_runtime.h>

#define BB 512
#define TT 512
#define KK 128

typedef __attribute__((ext_vector_type(8))) short short8;   // 8 x bf16 bits
typedef __attribute__((ext_vector_type(4))) float f32x4;

// f32 -> bf16 bits, round-to-nearest-even (finite values)
__device__ __forceinline__ unsigned short f2bf(float f) {
  unsigned u = __float_as_uint(f);
  unsigned r = ((u >> 16) & 1u) + 0x7fffu;
  return (unsigned short)((u + r) >> 16);
}
__device__ __forceinline__ float bf2f(unsigned short h) {
  return __uint_as_float(((unsigned)h) << 16);
}
__device__ __forceinline__ int fexpo(float f) {
  return (int)((__float_as_uint(f) >> 23) & 0xFF) - 127;
}
// Drain LDS ops only; global prefetch loads stay in flight across the barrier.
__device__ __forceinline__ void lds_barrier() {
  asm volatile("s_waitcnt lgkmcnt(0)\n\ts_barrier" ::: "memory");
}

// K1: one block per (batch, direction) half-chain. 256 threads = 4 waves;
// wave w owns output columns [32w, 32w+32) = MFMA col-tiles 2w, 2w+1.
// dir=0 fwd:  w_t = u_t . (E^T w_{t-1}), t = 1..256           (256 steps)
// dir=1 bwd:  z_{t-1} = u_{t-1} . (E z_t), t = 510..257, then
//             y = E z_257 (plain)                              (255 steps)
// Scaled bf16 state in LDS, lagged power-of-2 rescale:
//   stored_new = matvec * 2^(pot*C - d), d = exponent of stored[0] being read,
//   M += d each step; true value = stored * 2^M.
// Row-replicated 16x16x32 bf16 MFMA (A k-chunk broadcast to all 16 rows).
// Final state vector + M + half-score -> workspace; K2 combines.
__global__ __launch_bounds__(256, 4) void crf_half_kernel(
    const float* __restrict__ pot, const int* __restrict__ tags,
    const float* __restrict__ trans, unsigned short* __restrict__ wsv,
    float* __restrict__ wsm) {
  const float C = 1.4426950408889634f;    // 1/ln2
  const int bid = blockIdx.x;
  const int b = bid >> 1, dir = bid & 1;
  const int tid = threadIdx.x;            // 0..255
  const int lane = tid & 63;
  const int wid = tid >> 6;               // wave = column quarter 0..3
  const int lg = lane >> 4;               // k-chunk group 0..3
  const int lc = lane & 15;               // column within 16-tile

  __shared__ alignas(16) unsigned short sbuf[2][KK];  // [parity][j]
  __shared__ int dbuf[2];
  __shared__ float red[4];

  const float* pb = pot + (size_t)b * TT * KK;

  // ---- half of the sequence score (fwd: pairs 0..255; bwd: 256..510) ----
  float sc;
  {
    int t = dir * 256 + tid;
    int tg = tags[b * TT + t];
    sc = pb[(size_t)t * KK + tg];
    if (t + 1 < TT) sc += trans[tg * KK + tags[b * TT + t + 1]];
  }
  #pragma unroll
  for (int off = 32; off; off >>= 1) sc += __shfl_xor(sc, off, 64);
  if (lane == 0) red[wid] = sc;

  // ---- B fragments for this wave's two tiles (bwd uses transposed E) ----
  short8 B0[4], B1[4];
  const int j0 = 32 * wid + lc, j1 = j0 + 16;
  #pragma unroll
  for (int kc = 0; kc < 4; ++kc) {
    #pragma unroll
    for (int e = 0; e < 8; ++e) {
      int k = 32 * kc + 8 * lg + e;
      float t0 = (dir == 0) ? trans[k * KK + j0] : trans[j0 * KK + k];
      float t1 = (dir == 0) ? trans[k * KK + j1] : trans[j1 * KK + k];
      B0[kc][e] = (short)f2bf(__builtin_amdgcn_exp2f(t0 * C));
      B1[kc][e] = (short)f2bf(__builtin_amdgcn_exp2f(t1 * C));
    }
  }

  // ---- init state: fwd u_0, bwd u_511 ----
  {
    int ri = dir ? (TT - 1) : 0;
    if (tid < KK) {
      float w0 = __builtin_amdgcn_exp2f(pb[(size_t)ri * KK + tid] * C);
      sbuf[0][tid] = f2bf(w0);
      if (tid == 0) dbuf[0] = fexpo(w0);
    }
  }
  __syncthreads();

  const int nst = dir ? 255 : 256;
  const int r0 = dir ? (TT - 2) : 1;
  const int st = dir ? -1 : 1;

  // 3-deep pot prefetch pipeline (2 columns per lane)
  float pA0 = pb[(size_t)r0 * KK + j0];
  float pA1 = pb[(size_t)r0 * KK + j1];
  float pB0 = pb[(size_t)(r0 + st) * KK + j0];
  float pB1 = pb[(size_t)(r0 + st) * KK + j1];
  float pC0 = pb[(size_t)(r0 + 2 * st) * KK + j0];
  float pC1 = pb[(size_t)(r0 + 2 * st) * KK + j1];
  float M = 0.f;

  for (int it = 0; it < nst; ++it) {
    const int p = it & 1, w = p ^ 1;
    const unsigned short* wp = &sbuf[p][8 * lg];
    short8 A0 = *(const short8*)(wp);         // w[     8lg + e]
    short8 A1 = *(const short8*)(wp + 32);    // w[32 + 8lg + e]
    short8 A2 = *(const short8*)(wp + 64);
    short8 A3 = *(const short8*)(wp + 96);
    int d = dbuf[p];
    int rn = r0 + st * (it + 3);              // always in [0, TT)
    float pN0 = pb[(size_t)rn * KK + j0];
    float pN1 = pb[(size_t)rn * KK + j1];
    const f32x4 z4 = {0.f, 0.f, 0.f, 0.f};
    f32x4 aP0, aQ0, aP1, aQ1;
    __builtin_amdgcn_s_setprio(1);
    aP0 = __builtin_amdgcn_mfma_f32_16x16x32_bf16(A0, B0[0], z4, 0, 0, 0);
    aQ0 = __builtin_amdgcn_mfma_f32_16x16x32_bf16(A2, B0[2], z4, 0, 0, 0);
    aP1 = __builtin_amdgcn_mfma_f32_16x16x32_bf16(A0, B1[0], z4, 0, 0, 0);
    aQ1 = __builtin_amdgcn_mfma_f32_16x16x32_bf16(A2, B1[2], z4, 0, 0, 0);
    aP0 = __builtin_amdgcn_mfma_f32_16x16x32_bf16(A1, B0[1], aP0, 0, 0, 0);
    aQ0 = __builtin_amdgcn_mfma_f32_16x16x32_bf16(A3, B0[3], aQ0, 0, 0, 0);
    aP1 = __builtin_amdgcn_mfma_f32_16x16x32_bf16(A1, B1[1], aP1, 0, 0, 0);
    aQ1 = __builtin_amdgcn_mfma_f32_16x16x32_bf16(A3, B1[3], aQ1, 0, 0, 0);
    __builtin_amdgcn_s_setprio(0);
    float z0 = aP0[0] + aQ0[0];               // rows replicated: [0] = col lc
    float z1 = aP1[0] + aQ1[0];
    const bool lastB = dir && (it == nst - 1);  // y = E z (no u factor)
    float pe0 = lastB ? 0.f : pA0;
    float pe1 = lastB ? 0.f : pA1;
    float fd = (float)(-d);
    float v0 = z0 * __builtin_amdgcn_exp2f(fmaf(pe0, C, fd));
    float v1 = z1 * __builtin_amdgcn_exp2f(fmaf(pe1, C, fd));
    M += (float)d;
    if (lane < 16) {                          // all 4 lane-groups replicate
      sbuf[w][j0] = f2bf(v0);
      sbuf[w][j1] = f2bf(v1);
    }
    if (tid == 0) dbuf[w] = fexpo(v0);        // col 0 owner
    pA0 = pB0; pA1 = pB1; pB0 = pC0; pB1 = pC1; pC0 = pN0; pC1 = pN1;
    lds_barrier();   // drains LDS only; pot prefetches stay in flight
  }

  // ---- export final state + M + half score ----
  const int fin = nst & 1;   // fwd: parity 0, bwd: parity 1
  if (tid < KK) wsv[(size_t)bid * KK + tid] = sbuf[fin][tid];
  if (tid == 0) {
    wsm[2 * bid] = M;
    wsm[2 * bid + 1] = red[0] + red[1] + red[2] + red[3];
  }
}

// K2: combine halves. One wave per batch element: Z*2^(Mf+Mb) = wF . yB.
__global__ __launch_bounds__(256) void crf_combine_kernel(
    const unsigned short* __restrict__ wsv, const float* __restrict__ wsm,
    float* __restrict__ out) {
  const float LN2 = 0.6931471805599453f;
  const int tid = threadIdx.x;
  const int lane = tid & 63, wid = tid >> 6;
  const int b = blockIdx.x * 4 + wid;
  const unsigned short* wf = wsv + (size_t)(2 * b) * KK;
  const unsigned short* yb = wsv + (size_t)(2 * b + 1) * KK;
  float pr = bf2f(wf[lane]) * bf2f(yb[lane]) +
             bf2f(wf[lane + 64]) * bf2f(yb[lane + 64]);
  #pragma unroll
  for (int off = 32; off; off >>= 1) pr += __shfl_xor(pr, off, 64);
  if (lane == 0) {
    float Mf  = wsm[4 * b + 0], scF = wsm[4 * b + 1];
    float Mb  = wsm[4 * b + 2], scB = wsm[4 * b + 3];
    float logZ = (Mf + Mb + __builtin_amdgcn_logf(pr)) * LN2;
    out[b] = (scF + scB) - logZ;
  }
}

extern "C" void kernel_launch(void* const* d_in, const int* in_sizes, int n_in,
                              void* d_out, int out_size, void* d_ws, size_t ws_size,
                              hipStream_t stream) {
  const float* pot = (const float*)d_in[0];
  const int* tags = (const int*)d_in[1];
  const float* trans = (const float*)d_in[2];
  float* out = (float*)d_out;
  unsigned short* wsv = (unsigned short*)d_ws;                 // 1024 x 128 bf16
  float* wsm = (float*)((char*)d_ws + (size_t)2 * BB * KK * 2); // 1024 x {M, score}
  crf_half_kernel<<<2 * BB, 256, 0, stream>>>(pot, tags, trans, wsv, wsm);
  crf_combine_kernel<<<BB / 4, 256, 0, stream>>>(wsv, wsm, out);
}

// Round 10
// 136.747 us; speedup vs baseline: 1.1844x; 1.0868x over previous
//
#include <hip/hip_runtime.h>

#define BB 512
#define TT 512
#define KK 128

typedef __attribute__((ext_vector_type(8))) short short8;   // 8 x bf16 bits
typedef __attribute__((ext_vector_type(4))) float f32x4;

// f32 -> bf16 bits, round-to-nearest-even (finite values)
__device__ __forceinline__ unsigned short f2bf(float f) {
  unsigned u = __float_as_uint(f);
  unsigned r = ((u >> 16) & 1u) + 0x7fffu;
  return (unsigned short)((u + r) >> 16);
}
__device__ __forceinline__ float bf2f(unsigned short h) {
  return __uint_as_float(((unsigned)h) << 16);
}
__device__ __forceinline__ int fexpo(float f) {
  return (int)((__float_as_uint(f) >> 23) & 0xFF) - 127;
}

// Non-draining barrier: drain LDS ops (cross-wave ds_write->ds_read handoff)
// but leave global prefetch loads IN FLIGHT across the barrier.
__device__ __forceinline__ void lds_barrier() {
  asm volatile("s_waitcnt lgkmcnt(0)\n\ts_barrier" ::: "memory");
}

// One block per batch element, 512 threads = 8 waves.
// Waves 0-3: FORWARD half  w_t = u_t . (E^T w_{t-1}),  t = 1..256  (256 steps)
// Waves 4-7: BACKWARD half y_{t-1} = u_{t-1} . (E y_t), t = 511..257 (255 steps)
//   Z = beta_256^T w_256 -> dot at the meet.
// Scaled vectors (bf16 in LDS), lagged power-of-2 rescale:
//   stored_new = (matvec) * 2^(pot*C - d),  d = exponent of previous stored[0],
//   M += d each step;  true value = stored * 2^M.
// Matvec via row-replicated 16x16x32 bf16 MFMA (A chunk broadcast to all rows).
// pot prefetch: 4-PHASE UNROLLED pipeline with distinct registers per phase —
// no register rotation, so the compiler never emits a vmcnt(0)-at-copy stall;
// each phase's value is consumed 4 steps after issue (~2000+ cyc of slack).
__global__ __launch_bounds__(512, 2) void crf_fwd_kernel(
    const float* __restrict__ pot, const int* __restrict__ tags,
    const float* __restrict__ trans, float* __restrict__ out) {
  const float C = 1.4426950408889634f;    // 1/ln2
  const float LN2 = 0.6931471805599453f;
  const int b = blockIdx.x;
  const int tid = threadIdx.x;            // 0..511
  const int lane = tid & 63;
  const int wid = tid >> 6;               // 0..7
  const int grp = wid >> 2;               // 0 = fwd, 1 = bwd
  const int wq = wid & 3;                 // column quarter within group
  const int lg = lane >> 4;               // k-chunk group 0..3
  const int lc = lane & 15;               // column within 16-tile

  __shared__ alignas(16) unsigned short sbuf[2][2][KK];  // [grp][parity][j]
  __shared__ int dbuf[2][2];
  __shared__ float red[12];

  const float* pb = pot + (size_t)b * TT * KK;

  // ---- sequence score: thread tid handles time-step tid ----
  float sc;
  {
    int tg0 = tags[b * TT + tid];
    sc = pb[(size_t)tid * KK + tg0];
    if (tid + 1 < TT) sc += trans[tg0 * KK + tags[b * TT + tid + 1]];
  }
  #pragma unroll
  for (int off = 32; off; off >>= 1) sc += __shfl_xor(sc, off, 64);
  if (lane == 0) red[wid] = sc;

  // ---- constant B fragments (fwd: E[k][j]; bwd: E[j][k] i.e. transposed) ----
  short8 B0[4], B1[4];
  const int c0 = 2 * wq, c1 = 2 * wq + 1;
  #pragma unroll
  for (int q = 0; q < 4; ++q) {
    #pragma unroll
    for (int e = 0; e < 8; ++e) {
      int k = 32 * q + 8 * lg + e;
      int ja = 16 * c0 + lc, jb = 16 * c1 + lc;
      float t0 = (grp == 0) ? trans[k * KK + ja] : trans[ja * KK + k];
      float t1 = (grp == 0) ? trans[k * KK + jb] : trans[jb * KK + k];
      B0[q][e] = (short)f2bf(__builtin_amdgcn_exp2f(t0 * C));
      B1[q][e] = (short)f2bf(__builtin_amdgcn_exp2f(t1 * C));
    }
  }

  // ---- init: fwd sbuf[0][0] = u_0;  bwd sbuf[1][0] = u_511 ----
  if (tid < KK) {
    float w0 = __builtin_amdgcn_exp2f(pb[tid] * C);
    sbuf[0][0][tid] = f2bf(w0);
    if (tid == 0) dbuf[0][0] = fexpo(w0);
  } else if (tid >= 256 && tid < 256 + KK) {
    int j = tid - 256;
    float y0 = __builtin_amdgcn_exp2f(pb[(size_t)(TT - 1) * KK + j] * C);
    sbuf[1][0][j] = f2bf(y0);
    if (j == 0) dbuf[1][0] = fexpo(y0);
  }
  __syncthreads();
  const float score = red[0] + red[1] + red[2] + red[3] +
                      red[4] + red[5] + red[6] + red[7];

  const int nst = grp ? 255 : 256;
  const int r0 = grp ? (TT - 2) : 1;
  const int st = grp ? -1 : 1;
  const int j0 = 32 * wq + lc, j1 = j0 + 16;
  float M = 0.f;

  // 4-phase pot pipeline: phase f holds pot row r0 + st*(it) for it%4 == f.
  float p0a = pb[(size_t)(r0 + 0 * st) * KK + j0];
  float p0b = pb[(size_t)(r0 + 0 * st) * KK + j1];
  float p1a = pb[(size_t)(r0 + 1 * st) * KK + j0];
  float p1b = pb[(size_t)(r0 + 1 * st) * KK + j1];
  float p2a = pb[(size_t)(r0 + 2 * st) * KK + j0];
  float p2b = pb[(size_t)(r0 + 2 * st) * KK + j1];
  float p3a = pb[(size_t)(r0 + 3 * st) * KK + j0];
  float p3b = pb[(size_t)(r0 + 3 * st) * KK + j1];

  auto step = [&](int it, float& qa, float& qb) {
    const int p = it & 1, w = p ^ 1;
    const unsigned short* wp = &sbuf[grp][p][8 * lg];
    short8 A0 = *(const short8*)(wp);
    short8 A1 = *(const short8*)(wp + 32);
    short8 A2 = *(const short8*)(wp + 64);
    short8 A3 = *(const short8*)(wp + 96);
    int d = dbuf[grp][p];
    float cp0 = qa, cp1 = qb;                    // value loaded 4 steps ago
    // reload this phase for step it+4 (fwd: rn<=260<512; bwd: rn>=252>=0)
    int rn = r0 + st * (it + 4);
    qa = pb[(size_t)rn * KK + j0];
    qb = pb[(size_t)rn * KK + j1];
    const f32x4 z4 = {0.f, 0.f, 0.f, 0.f};
    f32x4 aP0, aQ0, aP1, aQ1;
    __builtin_amdgcn_s_setprio(1);
    aP0 = __builtin_amdgcn_mfma_f32_16x16x32_bf16(A0, B0[0], z4, 0, 0, 0);
    aQ0 = __builtin_amdgcn_mfma_f32_16x16x32_bf16(A2, B0[2], z4, 0, 0, 0);
    aP1 = __builtin_amdgcn_mfma_f32_16x16x32_bf16(A0, B1[0], z4, 0, 0, 0);
    aQ1 = __builtin_amdgcn_mfma_f32_16x16x32_bf16(A2, B1[2], z4, 0, 0, 0);
    aP0 = __builtin_amdgcn_mfma_f32_16x16x32_bf16(A1, B0[1], aP0, 0, 0, 0);
    aQ0 = __builtin_amdgcn_mfma_f32_16x16x32_bf16(A3, B0[3], aQ0, 0, 0, 0);
    aP1 = __builtin_amdgcn_mfma_f32_16x16x32_bf16(A1, B1[1], aP1, 0, 0, 0);
    aQ1 = __builtin_amdgcn_mfma_f32_16x16x32_bf16(A3, B1[3], aQ1, 0, 0, 0);
    __builtin_amdgcn_s_setprio(0);
    float z0 = aP0[0] + aQ0[0];                  // rows replicated: [0]=col lc
    float z1 = aP1[0] + aQ1[0];
    const bool lastB = (grp == 1) && (it == nst - 1);  // y = E z (no u factor)
    float pe0 = lastB ? 0.f : cp0;
    float pe1 = lastB ? 0.f : cp1;
    float fd = (float)(-d);
    float v0 = z0 * __builtin_amdgcn_exp2f(fmaf(pe0, C, fd));
    float v1 = z1 * __builtin_amdgcn_exp2f(fmaf(pe1, C, fd));
    M += (float)d;
    if (lane < 16) {                             // 4 lane-groups replicate
      sbuf[grp][w][j0] = f2bf(v0);
      sbuf[grp][w][j1] = f2bf(v1);
    }
    if (lane == 0 && wq == 0) dbuf[grp][w] = fexpo(v0);
    lds_barrier();   // lgkmcnt(0)+s_barrier; global loads stay in flight
  };

  const int nq = nst >> 2;                       // fwd 64, bwd 63
  for (int itq = 0; itq < nq; ++itq) {
    int it = itq << 2;
    step(it + 0, p0a, p0b);
    step(it + 1, p1a, p1b);
    step(it + 2, p2a, p2b);
    step(it + 3, p3a, p3b);
  }
  // bwd tail: steps 252,253,254 (phases 0,1,2 already hold their pot rows)
  if (grp == 1) {
    step(252, p0a, p0b);
    step(253, p1a, p1b);
    step(254, p2a, p2b);
  }

  // ---- meet: Z = 2^(Mf+Mb) * sum_j wF[j] * yB[j] ----
  // fwd final: it=255 wrote parity 0;  bwd final: it=254 wrote parity 1.
  if (lane == 0 && wq == 0) red[10 + grp] = M;   // Mf -> red[10], Mb -> red[11]
  __syncthreads();
  if (tid < KK) {
    float prod = bf2f(sbuf[0][0][tid]) * bf2f(sbuf[1][1][tid]);
    #pragma unroll
    for (int off = 32; off; off >>= 1) prod += __shfl_xor(prod, off, 64);
    if (lane == 0) red[8 + wid] = prod;          // wid 0,1
  }
  __syncthreads();
  if (tid == 0) {
    float S = red[8] + red[9];
    float logZ = (red[10] + red[11] + __builtin_amdgcn_logf(S)) * LN2;
    out[b] = score - logZ;
  }
}

extern "C" void kernel_launch(void* const* d_in, const int* in_sizes, int n_in,
                              void* d_out, int out_size, void* d_ws, size_t ws_size,
                              hipStream_t stream) {
  const float* pot = (const float*)d_in[0];
  const int* tags = (const int*)d_in[1];
  const float* trans = (const float*)d_in[2];
  float* out = (float*)d_out;
  crf_fwd_kernel<<<BB, 512, 0, stream>>>(pot, tags, trans, out);
}

// Round 11
// 116.197 us; speedup vs baseline: 1.3938x; 1.1769x over previous
//
#include <hip/hip_runtime.h>

#define BB 512
#define TT 512
#define KK 128

typedef __attribute__((ext_vector_type(8))) short short8;   // 8 x bf16 bits
typedef __attribute__((ext_vector_type(4))) float f32x4;

// f32 -> bf16 bits, round-to-nearest-even (finite values)
__device__ __forceinline__ unsigned short f2bf(float f) {
  unsigned u = __float_as_uint(f);
  unsigned r = ((u >> 16) & 1u) + 0x7fffu;
  return (unsigned short)((u + r) >> 16);
}
__device__ __forceinline__ float bf2f(unsigned short h) {
  return __uint_as_float(((unsigned)h) << 16);
}
__device__ __forceinline__ int fexpo(float f) {
  return (int)((__float_as_uint(f) >> 23) & 0xFF) - 127;
}
// Drain LDS ops only; global prefetch loads stay in flight across the barrier.
__device__ __forceinline__ void lds_barrier() {
  asm volatile("s_waitcnt lgkmcnt(0)\n\ts_barrier" ::: "memory");
}

// One block per batch element, 256 threads = 4 waves.
// Waves 0-1: FORWARD half  w_t = u_t . (E^T w_{t-1}),  t = 1..256  (256 steps)
// Waves 2-3: BACKWARD half y_{t-1} = u_{t-1} . (E y_t), t = 511..257 (255 steps)
//   Z = beta_256^T w_256 -> dot at the meet.
// Each wave owns 64 output columns = 4 MFMA col-tiles x 4 k-chunks = 16 MFMAs
// (row-replicated 16x16x32 bf16: A k-chunk broadcast to all 16 rows).
// Epilogue is 1 column per lane (lane l of wave-half wh owns col 64*wh + l).
// Scaled vectors (bf16 in LDS), lagged power-of-2 rescale:
//   stored_new = matvec * 2^(pot*C - d), d = exponent of previous stored[0],
//   M += d each step; true value = stored * 2^M.
// pot prefetch: 4-phase unrolled pipeline, distinct register per phase.
__global__ __launch_bounds__(256, 2) void crf_fwd_kernel(
    const float* __restrict__ pot, const int* __restrict__ tags,
    const float* __restrict__ trans, float* __restrict__ out) {
  const float C = 1.4426950408889634f;    // 1/ln2
  const float LN2 = 0.6931471805599453f;
  const int b = blockIdx.x;
  const int tid = threadIdx.x;            // 0..255
  const int lane = tid & 63;
  const int wid = tid >> 6;               // 0..3
  const int grp = wid >> 1;               // 0 = fwd, 1 = bwd
  const int wh = wid & 1;                 // wave half within direction
  const int lg = lane >> 4;               // k-chunk lane-group 0..3
  const int lc = lane & 15;               // column within 16-tile

  __shared__ alignas(16) unsigned short sbuf[2][2][KK];  // [grp][parity][j]
  __shared__ int dbuf[2][2];
  __shared__ float red[12];

  const float* pb = pot + (size_t)b * TT * KK;

  // ---- sequence score: thread tid covers time-steps tid and tid+256 ----
  float sc;
  {
    int t0 = tid, t1 = tid + 256;
    int tg0 = tags[b * TT + t0];
    int tg1 = tags[b * TT + t1];
    sc = pb[(size_t)t0 * KK + tg0] + pb[(size_t)t1 * KK + tg1];
    sc += trans[tg0 * KK + tags[b * TT + t0 + 1]];
    if (t1 + 1 < TT) sc += trans[tg1 * KK + tags[b * TT + t1 + 1]];
  }
  #pragma unroll
  for (int off = 32; off; off >>= 1) sc += __shfl_xor(sc, off, 64);
  if (lane == 0) red[wid] = sc;

  // ---- B fragments: 4 tiles x 4 k-chunks (bwd: transposed E) ----
  short8 Bf[4][4];
  #pragma unroll
  for (int q = 0; q < 4; ++q) {
    const int j = 64 * wh + 16 * q + lc;
    #pragma unroll
    for (int kc = 0; kc < 4; ++kc) {
      #pragma unroll
      for (int e = 0; e < 8; ++e) {
        int k = 32 * kc + 8 * lg + e;
        float tv = (grp == 0) ? trans[k * KK + j] : trans[j * KK + k];
        Bf[q][kc][e] = (short)f2bf(__builtin_amdgcn_exp2f(tv * C));
      }
    }
  }

  // ---- init: fwd sbuf[0][0] = u_0;  bwd sbuf[1][0] = u_511 ----
  if (tid < KK) {
    float w0 = __builtin_amdgcn_exp2f(pb[tid] * C);
    sbuf[0][0][tid] = f2bf(w0);
    if (tid == 0) dbuf[0][0] = fexpo(w0);
  } else if (tid < 2 * KK) {
    int j = tid - KK;
    float y0 = __builtin_amdgcn_exp2f(pb[(size_t)(TT - 1) * KK + j] * C);
    sbuf[1][0][j] = f2bf(y0);
    if (j == 0) dbuf[1][0] = fexpo(y0);
  }
  __syncthreads();
  const float score = red[0] + red[1] + red[2] + red[3];

  const int nst = grp ? 255 : 256;
  const int r0 = grp ? (TT - 2) : 1;
  const int st = grp ? -1 : 1;
  const int jl = 64 * wh + lane;          // this lane's output column
  float M = 0.f;
  const f32x4 kZero = {0.f, 0.f, 0.f, 0.f};

  // 4-phase pot pipeline, one float per phase (one column per lane)
  float p0 = pb[(size_t)(r0 + 0 * st) * KK + jl];
  float p1 = pb[(size_t)(r0 + 1 * st) * KK + jl];
  float p2 = pb[(size_t)(r0 + 2 * st) * KK + jl];
  float p3 = pb[(size_t)(r0 + 3 * st) * KK + jl];

  auto step = [&](int it, float& q) {
    const int p = it & 1, wr = p ^ 1;
    const unsigned short* wp = &sbuf[grp][p][8 * lg];
    short8 A0 = *(const short8*)(wp);         // w[      8lg + e]
    short8 A1 = *(const short8*)(wp + 32);    // w[ 32 + 8lg + e]
    short8 A2 = *(const short8*)(wp + 64);
    short8 A3 = *(const short8*)(wp + 96);
    int d = dbuf[grp][p];
    float cp = q;                             // pot value loaded 4 steps ago
    int rn = r0 + st * (it + 4);              // fwd <=260, bwd >=252: in range
    q = pb[(size_t)rn * KK + jl];
    f32x4 a0, a1, a2, a3;
    __builtin_amdgcn_s_setprio(1);
    a0 = __builtin_amdgcn_mfma_f32_16x16x32_bf16(A3, Bf[0][3], kZero, 0, 0, 0);
    a1 = __builtin_amdgcn_mfma_f32_16x16x32_bf16(A3, Bf[1][3], kZero, 0, 0, 0);
    a2 = __builtin_amdgcn_mfma_f32_16x16x32_bf16(A3, Bf[2][3], kZero, 0, 0, 0);
    a3 = __builtin_amdgcn_mfma_f32_16x16x32_bf16(A3, Bf[3][3], kZero, 0, 0, 0);
    a0 = __builtin_amdgcn_mfma_f32_16x16x32_bf16(A2, Bf[0][2], a0, 0, 0, 0);
    a1 = __builtin_amdgcn_mfma_f32_16x16x32_bf16(A2, Bf[1][2], a1, 0, 0, 0);
    a2 = __builtin_amdgcn_mfma_f32_16x16x32_bf16(A2, Bf[2][2], a2, 0, 0, 0);
    a3 = __builtin_amdgcn_mfma_f32_16x16x32_bf16(A2, Bf[3][2], a3, 0, 0, 0);
    a0 = __builtin_amdgcn_mfma_f32_16x16x32_bf16(A1, Bf[0][1], a0, 0, 0, 0);
    a1 = __builtin_amdgcn_mfma_f32_16x16x32_bf16(A1, Bf[1][1], a1, 0, 0, 0);
    a2 = __builtin_amdgcn_mfma_f32_16x16x32_bf16(A1, Bf[2][1], a2, 0, 0, 0);
    a3 = __builtin_amdgcn_mfma_f32_16x16x32_bf16(A1, Bf[3][1], a3, 0, 0, 0);
    a0 = __builtin_amdgcn_mfma_f32_16x16x32_bf16(A0, Bf[0][0], a0, 0, 0, 0);
    a1 = __builtin_amdgcn_mfma_f32_16x16x32_bf16(A0, Bf[1][0], a1, 0, 0, 0);
    a2 = __builtin_amdgcn_mfma_f32_16x16x32_bf16(A0, Bf[2][0], a2, 0, 0, 0);
    a3 = __builtin_amdgcn_mfma_f32_16x16x32_bf16(A0, Bf[3][0], a3, 0, 0, 0);
    __builtin_amdgcn_s_setprio(0);
    // lane's tile = lg; rows replicated so [0] = col lc of that tile
    float z = (lg == 0) ? a0[0] : ((lg == 1) ? a1[0] : ((lg == 2) ? a2[0] : a3[0]));
    const bool lastB = (grp == 1) && (it == nst - 1);  // y = E z (no u factor)
    float pe = lastB ? 0.f : cp;
    float v = z * __builtin_amdgcn_exp2f(fmaf(pe, C, (float)(-d)));
    M += (float)d;
    sbuf[grp][wr][jl] = f2bf(v);
    if (lane == 0 && wh == 0) dbuf[grp][wr] = fexpo(v);
    lds_barrier();   // lgkmcnt(0)+s_barrier; global loads stay in flight
  };

  const int nq = nst >> 2;                  // fwd 64, bwd 63
  for (int itq = 0; itq < nq; ++itq) {
    int it = itq << 2;
    step(it + 0, p0);
    step(it + 1, p1);
    step(it + 2, p2);
    step(it + 3, p3);
  }
  if (grp == 1) {                           // bwd tail: steps 252..254
    step(252, p0);
    step(253, p1);
    step(254, p2);
    lds_barrier();                          // equalize barrier count (255+1=256)
  }

  // ---- meet: Z = 2^(Mf+Mb) * sum_j wF[j] * yB[j] ----
  // fwd final: it=255 wrote parity 0;  bwd final: it=254 wrote parity 1.
  if (lane == 0 && wh == 0) red[10 + grp] = M;   // Mf->red[10], Mb->red[11]
  __syncthreads();
  if (tid < KK) {
    float prod = bf2f(sbuf[0][0][tid]) * bf2f(sbuf[1][1][tid]);
    #pragma unroll
    for (int off = 32; off; off >>= 1) prod += __shfl_xor(prod, off, 64);
    if (lane == 0) red[8 + wid] = prod;          // wid 0,1
  }
  __syncthreads();
  if (tid == 0) {
    float S = red[8] + red[9];
    float logZ = (red[10] + red[11] + __builtin_amdgcn_logf(S)) * LN2;
    out[b] = score - logZ;
  }
}

extern "C" void kernel_launch(void* const* d_in, const int* in_sizes, int n_in,
                              void* d_out, int out_size, void* d_ws, size_t ws_size,
                              hipStream_t stream) {
  const float* pot = (const float*)d_in[0];
  const int* tags = (const int*)d_in[1];
  const float* trans = (const float*)d_in[2];
  float* out = (float*)d_out;
  crf_fwd_kernel<<<BB, 256, 0, stream>>>(pot, tags, trans, out);
}